// Round 1
// baseline (63.620 us; speedup 1.0000x reference)
//
#include <hip/hip_runtime.h>

#define BOUNDING_PERC 0.05f

// ---------------------------------------------------------------------------
// Kernel 1: ufaces[b,x] = dot( kernel[b,x,:] @ W + bias , source[b,x,:,:] )
// One thread handles 4 consecutive faces so every global access is an
// aligned float4:
//   kernel : 4 faces * 4 f32 = 4 x float4   (64 B)
//   source : 4 faces * 9 f32 = 9 x float4   (144 B, 16B-aligned since 36*4q)
//   out    : 1 x float4
// ---------------------------------------------------------------------------
__global__ __launch_bounds__(256) void ufaces_kernel(
    const float4* __restrict__ k4,    // (b*nfaces) float4's
    const float4* __restrict__ s4,    // (b*nfaces*9/4) float4's
    const float*  __restrict__ W,     // [4][9]
    const float*  __restrict__ bias,  // [9]
    float4*       __restrict__ out,   // (b*nfaces/4) float4's
    int nquads)
{
    int q = blockIdx.x * blockDim.x + threadIdx.x;
    if (q >= nquads) return;

    // Uniform weights -> scalar loads / SGPRs
    float Wr[4][9];
#pragma unroll
    for (int i = 0; i < 4; ++i)
#pragma unroll
        for (int s = 0; s < 9; ++s)
            Wr[i][s] = W[i * 9 + s];
    float br[9];
#pragma unroll
    for (int s = 0; s < 9; ++s) br[s] = bias[s];

    float4 kq[4];
#pragma unroll
    for (int f = 0; f < 4; ++f) kq[f] = k4[4 * q + f];

    float4 sv[9];
#pragma unroll
    for (int j = 0; j < 9; ++j) sv[j] = s4[9 * q + j];
    const float* S = reinterpret_cast<const float*>(sv);

    float4 res;
    float* rp = reinterpret_cast<float*>(&res);
#pragma unroll
    for (int f = 0; f < 4; ++f) {
        const float k0 = kq[f].x, k1 = kq[f].y, k2 = kq[f].z, k3 = kq[f].w;
        float acc = 0.0f;
#pragma unroll
        for (int s = 0; s < 9; ++s) {
            float c = br[s];
            c = fmaf(k0, Wr[0][s], c);
            c = fmaf(k1, Wr[1][s], c);
            c = fmaf(k2, Wr[2][s], c);
            c = fmaf(k3, Wr[3][s], c);
            acc = fmaf(c, S[9 * f + s], acc);
        }
        rp[f] = acc;
    }
    out[q] = res;
}

// ---------------------------------------------------------------------------
// Kernel 2: bounded fixup at the gathered positions (read-modify-write on out)
// ---------------------------------------------------------------------------
__global__ __launch_bounds__(256) void bound_kernel(
    const float* __restrict__ uc,   // (b*ncells)
    const int*   __restrict__ pos,  // (nb)
    const int*   __restrict__ own,  // (nb)
    const int*   __restrict__ nei,  // (nb)
    float*       __restrict__ out,  // (b*nfaces)
    int nb, int nfaces, int ncells, int nbatch)
{
    int idx = blockIdx.x * blockDim.x + threadIdx.x;
    if (idx >= nbatch * nb) return;
    int j  = idx % nb;
    int bb = idx / nb;

    int p = pos[j];
    float uf = out[bb * nfaces + p];
    float o  = uc[bb * ncells + own[j]];
    float n  = uc[bb * ncells + nei[j]];

    float smax = fmaxf(o, n);
    float smin = fminf(o, n);
    float flux = 0.5f * (o + n);
    float up   = (flux >= 0.0f) ? o : n;
    float hi   = smax + BOUNDING_PERC * fabsf(smax);
    float lo   = smin - BOUNDING_PERC * fabsf(smin);
    bool valid = (uf >= lo) && (uf <= hi);
    out[bb * nfaces + p] = valid ? uf : up;
}

extern "C" void kernel_launch(void* const* d_in, const int* in_sizes, int n_in,
                              void* d_out, int out_size, void* d_ws, size_t ws_size,
                              hipStream_t stream)
{
    const float* kernel_in = (const float*)d_in[0];  // (b, nfaces, 4)
    const float* source    = (const float*)d_in[1];  // (b, nfaces, 3, 3)
    const float* ucenters  = (const float*)d_in[2];  // (b, ncells)
    const float* W         = (const float*)d_in[3];  // (4, 9)
    const float* bias      = (const float*)d_in[4];  // (9,)
    const int*   positions = (const int*)d_in[5];    // (nb,)
    const int*   owners    = (const int*)d_in[6];    // (nb,)
    const int*   neighbours= (const int*)d_in[7];    // (nb,)
    float*       out       = (float*)d_out;          // (b, nfaces)

    const int b      = 4;
    const int in_dim = 4;
    const int nfaces = in_sizes[0] / (b * in_dim);
    const int ncells = in_sizes[2] / b;
    const int nb     = in_sizes[5];

    // Pass 1: all faces
    const int nquads = (b * nfaces) / 4;   // nfaces divisible by 4 here
    {
        dim3 block(256);
        dim3 grid((nquads + 255) / 256);
        ufaces_kernel<<<grid, block, 0, stream>>>(
            (const float4*)kernel_in, (const float4*)source, W, bias,
            (float4*)out, nquads);
    }

    // Pass 2: bounded fixup at positions
    {
        int total = b * nb;
        dim3 block(256);
        dim3 grid((total + 255) / 256);
        bound_kernel<<<grid, block, 0, stream>>>(
            ucenters, positions, owners, neighbours, out,
            nb, nfaces, ncells, b);
    }
}

// Round 2
// 60.821 us; speedup vs baseline: 1.0460x; 1.0460x over previous
//
#include <hip/hip_runtime.h>

#define BOUNDING_PERC 0.05f

// ---------------------------------------------------------------------------
// Kernel 1: ufaces[b,x] = dot( kernel[b,x,:] @ W + bias , source[b,x,:,:] )
// One thread per face. 256 faces per block.
//   kernel : lane-consecutive float4 loads (coalesced, 1 KiB/wave-instr)
//   source : 36 B/face -> staged via LDS with coalesced float4 chunk loads
//            (576 float4 per block), then read 9 scalars/lane at dword
//            stride 9 (odd -> gcd(9,32)=1 -> bank-conflict-free)
//   out    : coalesced dword store
// Requires total_faces % 256 == 0 (true here: 4 * 1e6).
// ---------------------------------------------------------------------------
__global__ __launch_bounds__(256) void ufaces_kernel(
    const float4* __restrict__ k4,    // (total_faces) float4's
    const float4* __restrict__ s4,    // (total_faces*9/4) float4's
    const float*  __restrict__ W,     // [4][9]
    const float*  __restrict__ bias,  // [9]
    float*        __restrict__ out)   // (total_faces)
{
    __shared__ float s_src[2304];     // 256 faces * 9 f32 = 9216 B
    const int tid       = threadIdx.x;
    const int base_face = blockIdx.x << 8;

    // Cooperative coalesced stage: 576 float4 = 2304 floats
    {
        const float4* src_blk = s4 + ((size_t)base_face * 9) / 4;
        float4* sm4 = reinterpret_cast<float4*>(s_src);
        sm4[tid]       = src_blk[tid];
        sm4[tid + 256] = src_blk[tid + 256];
        if (tid < 64) sm4[tid + 512] = src_blk[tid + 512];
    }

    // Uniform weights -> scalar loads / SGPRs
    float Wr[4][9];
#pragma unroll
    for (int i = 0; i < 4; ++i)
#pragma unroll
        for (int s = 0; s < 9; ++s)
            Wr[i][s] = W[i * 9 + s];
    float br[9];
#pragma unroll
    for (int s = 0; s < 9; ++s) br[s] = bias[s];

    const float4 kv = k4[base_face + tid];

    __syncthreads();

    const float* S = &s_src[tid * 9];
    float acc = 0.0f;
#pragma unroll
    for (int s = 0; s < 9; ++s) {
        float c = br[s];
        c = fmaf(kv.x, Wr[0][s], c);
        c = fmaf(kv.y, Wr[1][s], c);
        c = fmaf(kv.z, Wr[2][s], c);
        c = fmaf(kv.w, Wr[3][s], c);
        acc = fmaf(c, S[s], acc);
    }
    out[base_face + tid] = acc;
}

// ---------------------------------------------------------------------------
// Kernel 2: bounded fixup at the gathered positions (read-modify-write on out)
// ---------------------------------------------------------------------------
__global__ __launch_bounds__(256) void bound_kernel(
    const float* __restrict__ uc,   // (b*ncells)
    const int*   __restrict__ pos,  // (nb)
    const int*   __restrict__ own,  // (nb)
    const int*   __restrict__ nei,  // (nb)
    float*       __restrict__ out,  // (b*nfaces)
    int nb, int nfaces, int ncells, int nbatch)
{
    int idx = blockIdx.x * blockDim.x + threadIdx.x;
    if (idx >= nbatch * nb) return;
    int j  = idx % nb;
    int bb = idx / nb;

    int p = pos[j];
    float uf = out[bb * nfaces + p];
    float o  = uc[bb * ncells + own[j]];
    float n  = uc[bb * ncells + nei[j]];

    float smax = fmaxf(o, n);
    float smin = fminf(o, n);
    float flux = 0.5f * (o + n);
    float up   = (flux >= 0.0f) ? o : n;
    float hi   = smax + BOUNDING_PERC * fabsf(smax);
    float lo   = smin - BOUNDING_PERC * fabsf(smin);
    bool valid = (uf >= lo) && (uf <= hi);
    out[bb * nfaces + p] = valid ? uf : up;
}

extern "C" void kernel_launch(void* const* d_in, const int* in_sizes, int n_in,
                              void* d_out, int out_size, void* d_ws, size_t ws_size,
                              hipStream_t stream)
{
    const float* kernel_in  = (const float*)d_in[0];  // (b, nfaces, 4)
    const float* source     = (const float*)d_in[1];  // (b, nfaces, 3, 3)
    const float* ucenters   = (const float*)d_in[2];  // (b, ncells)
    const float* W          = (const float*)d_in[3];  // (4, 9)
    const float* bias       = (const float*)d_in[4];  // (9,)
    const int*   positions  = (const int*)d_in[5];    // (nb,)
    const int*   owners     = (const int*)d_in[6];    // (nb,)
    const int*   neighbours = (const int*)d_in[7];    // (nb,)
    float*       out        = (float*)d_out;          // (b, nfaces)

    const int b      = 4;
    const int in_dim = 4;
    const int nfaces = in_sizes[0] / (b * in_dim);
    const int ncells = in_sizes[2] / b;
    const int nb     = in_sizes[5];

    const int total_faces = b * nfaces;       // 4,000,000 -> % 256 == 0

    // Pass 1: all faces
    {
        dim3 block(256);
        dim3 grid(total_faces / 256);
        ufaces_kernel<<<grid, block, 0, stream>>>(
            (const float4*)kernel_in, (const float4*)source, W, bias, out);
    }

    // Pass 2: bounded fixup at positions
    {
        int total = b * nb;
        dim3 block(256);
        dim3 grid((total + 255) / 256);
        bound_kernel<<<grid, block, 0, stream>>>(
            ucenters, positions, owners, neighbours, out,
            nb, nfaces, ncells, b);
    }
}